// Round 6
// baseline (1021.868 us; speedup 1.0000x reference)
//
#include <hip/hip_runtime.h>

// ---------------------------------------------------------------------------
// SLAYER-style spiking CNN forward pass, MI355X.  Round 6.
//
// psp (SRM alpha kernel) as double-exponential IIR cascade (exact):
//   g1[t] = x[t] + a*g1[t-1]; g2[t] = g1[t] + a*g2[t-1]; u = (e/tau)*(g2-g1)
//
// R6: dense1 sparse walk made branch-free: sentinel ctz + unconditional
// in-bounds load + v_fma_f64 with uniform 0/1 multiplier (adding +0.0 is
// IEEE-exact).  One branch per while-iteration instead of four; loads become
// hoistable (R5 was latency-bound at VALUBusy 15.7%).
// All accumulation in f64 for exact spike-pattern match.
// ---------------------------------------------------------------------------

namespace {
constexpr int B = 32, T = 100;
constexpr double A1 = 0.90483741803595957;  // exp(-1/10)
constexpr double CE = 0.27182818284590452;  // e/10

// workspace byte offsets
constexpr size_t OFF_M1 = 0;                                  // u32 [B*T][28]
constexpr size_t OFF_M2 = OFF_M1 + (size_t)B * T * 28 * 4;    // u32 [B*T][16][14]
constexpr size_t OFF_M4 = OFF_M2 + (size_t)B * T * 224 * 4;   // u64 [B*T][32]
constexpr size_t OFF_D5 = OFF_M4 + (size_t)B * T * 32 * 8;    // f64 [B*T][410]
constexpr size_t OFF_S5 = OFF_D5 + (size_t)B * T * 410 * 8;   // u8  [B*T][410]
constexpr size_t OFF_D6 = OFF_S5 + (size_t)B * T * 410;       // f64 [B*T][10]
constexpr size_t OFF_WT = OFF_D6 + (size_t)B * T * 10 * 8;    // f32 [1568][410]
}  // namespace

// Zero-extending wave-uniform u64 broadcast (readfirstlane returns int —
// implicit conversion would SIGN-extend; that was the R3/R4 bug).
__device__ inline unsigned long long uniform_u64(unsigned long long v) {
  unsigned int lo = (unsigned int)__builtin_amdgcn_readfirstlane((int)(unsigned int)v);
  unsigned int hi = (unsigned int)__builtin_amdgcn_readfirstlane((int)(unsigned int)(v >> 32));
  return ((unsigned long long)hi << 32) | (unsigned long long)lo;
}

// Stage 0: rate encode + bit-pack rows.
__global__ void k_encode_pack(const float* __restrict__ img, const float* __restrict__ ru,
                              unsigned int* __restrict__ m1) {
  int i = blockIdx.x * 256 + threadIdx.x;
  if (i >= B * 28 * T) return;
  int t = i % T;
  int y = (i / T) % 28;
  int b = i / (T * 28);
  unsigned int m = 0;
  const float* rb = ru + ((size_t)b * 784 + y * 28) * T + t;
  const float* ib = img + b * 784 + y * 28;
  for (int x = 0; x < 28; x++) {
    m |= (rb[(size_t)x * T] < ib[x]) ? (1u << x) : 0u;
  }
  m1[((size_t)b * T + t) * 28 + y] = m;
}

// Stage 1 fused: conv1 (1->16,5x5,pad2) + psp + spike + pool2 + psp + spike.
__global__ __launch_bounds__(256) void k_conv1(const unsigned int* __restrict__ m1,
                                               const float* __restrict__ w1,
                                               unsigned int* __restrict__ m2) {
  __shared__ double lut[160];        // [dy][32]
  __shared__ unsigned int mrow[32];  // rows iy=-2..29 at idx iy+2; guards 0
  __shared__ unsigned char spk[784];
  __shared__ unsigned char spkP[196];
  int o = blockIdx.x % 16, b = blockIdx.x / 16;
  int tid = threadIdx.x;
  if (tid < 160) {
    int dy = tid / 32, f = tid % 32;
    double v = 0.0;
    const float* wb = w1 + o * 25 + dy * 5;
#pragma unroll
    for (int dx = 0; dx < 5; dx++)
      if ((f >> dx) & 1) v += (double)wb[dx];
    lut[tid] = v;
  }
  if (tid < 32) mrow[tid] = 0;  // guard rows stay 0
  int y = tid / 7, xg = tid % 7;     // conv coords: 28 rows x 7 groups of 4 px
  int py = tid / 14, px = tid % 14;  // pooled coords
  bool act = tid < 196;
  double g1[4] = {0, 0, 0, 0}, g2[4] = {0, 0, 0, 0};
  double p1 = 0.0, p2 = 0.0;
  const unsigned int* m1b = m1 + (size_t)b * T * 28;
  unsigned int r = (tid < 28) ? m1b[tid] : 0u;  // prefetch t=0
  for (int t = 0; t < T; t++) {
    __syncthreads();
    if (tid < 28) mrow[tid + 2] = r << 2;  // pre-shifted
    __syncthreads();
    if (tid < 28 && t + 1 < T) r = m1b[(t + 1) * 28 + tid];  // prefetch t+1
    if (act) {
      double s0 = 0, s1 = 0, s2 = 0, s3 = 0;
      int xb = xg * 4;
#pragma unroll
      for (int dy = 0; dy < 5; dy++) {
        unsigned int m = mrow[y + dy];
        const double* ld = lut + dy * 32;
        s0 += ld[(m >> (xb + 0)) & 31];
        s1 += ld[(m >> (xb + 1)) & 31];
        s2 += ld[(m >> (xb + 2)) & 31];
        s3 += ld[(m >> (xb + 3)) & 31];
      }
      g1[0] = s0 + A1 * g1[0]; g2[0] = g1[0] + A1 * g2[0];
      g1[1] = s1 + A1 * g1[1]; g2[1] = g1[1] + A1 * g2[1];
      g1[2] = s2 + A1 * g1[2]; g2[2] = g1[2] + A1 * g2[2];
      g1[3] = s3 + A1 * g1[3]; g2[3] = g1[3] + A1 * g2[3];
      unsigned char* sp = spk + y * 28 + xb;
      sp[0] = (CE * (g2[0] - g1[0]) >= 1.0) ? 1 : 0;
      sp[1] = (CE * (g2[1] - g1[1]) >= 1.0) ? 1 : 0;
      sp[2] = (CE * (g2[2] - g1[2]) >= 1.0) ? 1 : 0;
      sp[3] = (CE * (g2[3] - g1[3]) >= 1.0) ? 1 : 0;
    }
    __syncthreads();
    if (act) {
      const unsigned char* r0 = spk + (2 * py) * 28 + 2 * px;
      int sum = (int)r0[0] + (int)r0[1] + (int)r0[28] + (int)r0[29];
      double s = 1.1 * (double)sum;
      p1 = s + A1 * p1;
      p2 = p1 + A1 * p2;
      spkP[tid] = (CE * (p2 - p1) >= 1.0) ? 1 : 0;
    }
    __syncthreads();
    if (tid < 14) {
      unsigned int m = 0;
      const unsigned char* rp = spkP + tid * 14;
#pragma unroll
      for (int xx = 0; xx < 14; xx++) m |= ((unsigned int)rp[xx]) << xx;
      m2[((size_t)(b * T + t) * 16 + o) * 14 + tid] = m;
    }
  }
}

// Stage 3 fused: conv2 (16->32,5x5,pad2) + psp + spike + pool2 + psp + spike.
// Emits pooled spikes as u64 ballot masks m4[bt][o] (bit p = pooled pos p).
__global__ __launch_bounds__(256) void k_conv2(const unsigned int* __restrict__ m2,
                                               const float* __restrict__ w2,
                                               unsigned long long* __restrict__ m4) {
  __shared__ double lut[2560];         // [ci][dy][32]  (20480 B)
  __shared__ unsigned int mrow2[288];  // [row 0..17][ci 0..15]; guard rows 0
  __shared__ unsigned char spk[196];
  int o = blockIdx.x % 32, b = blockIdx.x / 32;
  int tid = threadIdx.x;
  for (int e = tid; e < 2560; e += 256) {
    int ci = e / 160, rr = e % 160, dy = rr / 32, f = rr % 32;
    double v = 0.0;
    const float* wb = w2 + o * 400 + ci * 25 + dy * 5;
#pragma unroll
    for (int dx = 0; dx < 5; dx++)
      if ((f >> dx) & 1) v += (double)wb[dx];
    lut[e] = v;  // e == (ci*5+dy)*32 + f
  }
  for (int k = tid; k < 288; k += 256) mrow2[k] = 0;
  int y = tid / 14, x = tid % 14;
  int py = tid / 7, px = tid % 7;
  bool act = tid < 196;
  double g1 = 0.0, g2 = 0.0, p1 = 0.0, p2 = 0.0;
  const unsigned int* m2b = m2 + (size_t)b * T * 224;
  int ci = tid / 14, rr = tid % 14;
  unsigned int r = (tid < 224) ? m2b[tid] : 0u;  // prefetch t=0
  for (int t = 0; t < T; t++) {
    __syncthreads();
    if (tid < 224) mrow2[(rr + 2) * 16 + ci] = r << 2;  // pre-shifted
    __syncthreads();
    if (tid < 224 && t + 1 < T) r = m2b[(size_t)(t + 1) * 224 + tid];  // prefetch
    if (act) {
      double s = 0.0;
#pragma unroll
      for (int dy = 0; dy < 5; dy++) {
        const uint4* q = (const uint4*)(mrow2 + (y + dy) * 16);
        uint4 qa = q[0], qb = q[1], qc = q[2], qd = q[3];
        const double* ld = lut + dy * 32;
        s += ld[0 * 160 + ((qa.x >> x) & 31)];
        s += ld[1 * 160 + ((qa.y >> x) & 31)];
        s += ld[2 * 160 + ((qa.z >> x) & 31)];
        s += ld[3 * 160 + ((qa.w >> x) & 31)];
        s += ld[4 * 160 + ((qb.x >> x) & 31)];
        s += ld[5 * 160 + ((qb.y >> x) & 31)];
        s += ld[6 * 160 + ((qb.z >> x) & 31)];
        s += ld[7 * 160 + ((qb.w >> x) & 31)];
        s += ld[8 * 160 + ((qc.x >> x) & 31)];
        s += ld[9 * 160 + ((qc.y >> x) & 31)];
        s += ld[10 * 160 + ((qc.z >> x) & 31)];
        s += ld[11 * 160 + ((qc.w >> x) & 31)];
        s += ld[12 * 160 + ((qd.x >> x) & 31)];
        s += ld[13 * 160 + ((qd.y >> x) & 31)];
        s += ld[14 * 160 + ((qd.z >> x) & 31)];
        s += ld[15 * 160 + ((qd.w >> x) & 31)];
      }
      g1 = s + A1 * g1;
      g2 = g1 + A1 * g2;
      spk[tid] = (CE * (g2 - g1) >= 1.0) ? 1 : 0;
    }
    __syncthreads();
    bool sp = false;
    if (tid < 49) {
      const unsigned char* r0 = spk + (2 * py) * 14 + 2 * px;
      int sum = (int)r0[0] + (int)r0[1] + (int)r0[14] + (int)r0[15];
      double s = 1.1 * (double)sum;
      p1 = s + A1 * p1;
      p2 = p1 + A1 * p2;
      sp = (CE * (p2 - p1) >= 1.0);
    }
    unsigned long long bal = __ballot(sp);  // bits 0..48 live in wave 0
    if (tid == 0) m4[(size_t)(b * T + t) * 32 + o] = bal;
  }
}

// Transpose wf1 [410][1568] -> wt [1568][410] for coalesced dense1 reads.
__global__ void k_transpose(const float* __restrict__ wf1, float* __restrict__ wt) {
  int i = blockIdx.x * 256 + threadIdx.x;
  if (i >= 410 * 1568) return;
  int col = i % 410, row = i / 410;
  wt[i] = wf1[col * 1568 + row];
}

// Stage 5a: dense1 sparse matmul.  Wave = 64 o-lanes, 4 (b,t) columns/wave.
// Branch-free per-column body: sentinel ctz keeps the always-executed load
// in-bounds; v_fma_f64 with uniform 0/1 multiplier replaces the branch
// (adding +0.0 is IEEE-exact).  One branch per while-iteration total.
__global__ __launch_bounds__(256) void k_dense1(const unsigned long long* __restrict__ m4,
                                                const float* __restrict__ wt,
                                                double* __restrict__ d5) {
  int tid = threadIdx.x;
  int lane = tid & 63;
  int wv = tid >> 6;
  int o = blockIdx.x * 64 + lane;  // gridDim.x = 7
  bool store = o < 410;
  int osafe = store ? o : 409;
  int col0 = (blockIdx.y * 4 + wv) * 4;  // gridDim.y = 200
  const float* wb = wt + osafe;
  const unsigned long long* mm = m4 + (size_t)col0 * 32;
  double a0 = 0, a1 = 0, a2 = 0, a3 = 0;
  constexpr unsigned long long SENT = 1ULL << 48;  // ctz fallback -> row 48 (in-bounds)
  for (int ob = 0; ob < 32; ob++) {
    unsigned long long q0 = uniform_u64(mm[ob]);
    unsigned long long q1 = uniform_u64(mm[32 + ob]);
    unsigned long long q2 = uniform_u64(mm[64 + ob]);
    unsigned long long q3 = uniform_u64(mm[96 + ob]);
    const float* wob = wb + ob * 49 * 410;  // + i*410 stays < 410*1568 for i<=48
    while (q0 | q1 | q2 | q3) {
      {
        double mlt = q0 ? 1.0 : 0.0;
        int i = (int)__builtin_ctzll(q0 | SENT);
        q0 &= q0 - 1;
        a0 = __builtin_fma((double)wob[i * 410], mlt, a0);
      }
      {
        double mlt = q1 ? 1.0 : 0.0;
        int i = (int)__builtin_ctzll(q1 | SENT);
        q1 &= q1 - 1;
        a1 = __builtin_fma((double)wob[i * 410], mlt, a1);
      }
      {
        double mlt = q2 ? 1.0 : 0.0;
        int i = (int)__builtin_ctzll(q2 | SENT);
        q2 &= q2 - 1;
        a2 = __builtin_fma((double)wob[i * 410], mlt, a2);
      }
      {
        double mlt = q3 ? 1.0 : 0.0;
        int i = (int)__builtin_ctzll(q3 | SENT);
        q3 &= q3 - 1;
        a3 = __builtin_fma((double)wob[i * 410], mlt, a3);
      }
    }
  }
  if (store) {
    d5[(size_t)(col0 + 0) * 410 + o] = a0;
    d5[(size_t)(col0 + 1) * 410 + o] = a1;
    d5[(size_t)(col0 + 2) * 410 + o] = a2;
    d5[(size_t)(col0 + 3) * 410 + o] = a3;
  }
}

// Stage 5b: psp + spike over dense1 output.  One thread per (b,o).
__global__ void k_psp5(const double* __restrict__ d5, unsigned char* __restrict__ s5) {
  int tid = blockIdx.x * 256 + threadIdx.x;
  if (tid >= B * 410) return;
  int o = tid % 410, b = tid / 410;
  double g1 = 0.0, g2 = 0.0;
  for (int t = 0; t < T; t++) {
    double s = d5[(size_t)(b * T + t) * 410 + o];
    g1 = s + A1 * g1;
    g2 = g1 + A1 * g2;
    s5[(size_t)(b * T + t) * 410 + o] = (CE * (g2 - g1) >= 1.0) ? 1 : 0;
  }
}

// Stage 6a: dense2 matmul.  One thread per (bt,o).
__global__ void k_dense2(const unsigned char* __restrict__ s5, const float* __restrict__ wf2,
                         double* __restrict__ d6) {
  int tid = blockIdx.x * 256 + threadIdx.x;
  if (tid >= B * T * 10) return;
  int o = tid % 10, bt = tid / 10;
  const unsigned char* sr = s5 + (size_t)bt * 410;
  const float* wr = wf2 + o * 410;
  double s = 0.0;
  for (int i = 0; i < 410; i++) s += (double)wr[i] * (double)sr[i];
  d6[tid] = s;
}

// Stage 6b: final psp + spike -> d_out [b][o][t] f32.
__global__ void k_psp6(const double* __restrict__ d6, float* __restrict__ out) {
  int tid = blockIdx.x * 256 + threadIdx.x;
  if (tid >= B * 10) return;
  int o = tid % 10, b = tid / 10;
  double g1 = 0.0, g2 = 0.0;
  for (int t = 0; t < T; t++) {
    double s = d6[(size_t)(b * T + t) * 10 + o];
    g1 = s + A1 * g1;
    g2 = g1 + A1 * g2;
    out[(size_t)b * 1000 + o * 100 + t] = (CE * (g2 - g1) >= 1.0) ? 1.0f : 0.0f;
  }
}

extern "C" void kernel_launch(void* const* d_in, const int* in_sizes, int n_in,
                              void* d_out, int out_size, void* d_ws, size_t ws_size,
                              hipStream_t stream) {
  const float* img = (const float*)d_in[0];
  const float* ru = (const float*)d_in[1];
  const float* w1 = (const float*)d_in[2];
  const float* w2 = (const float*)d_in[3];
  const float* wf1 = (const float*)d_in[4];
  const float* wf2 = (const float*)d_in[5];

  unsigned char* ws = (unsigned char*)d_ws;
  unsigned int* m1 = (unsigned int*)(ws + OFF_M1);
  unsigned int* m2 = (unsigned int*)(ws + OFF_M2);
  unsigned long long* m4 = (unsigned long long*)(ws + OFF_M4);
  double* d5 = (double*)(ws + OFF_D5);
  unsigned char* s5 = ws + OFF_S5;
  double* d6 = (double*)(ws + OFF_D6);
  float* wt = (float*)(ws + OFF_WT);
  float* out = (float*)d_out;

  k_encode_pack<<<(B * 28 * T + 255) / 256, 256, 0, stream>>>(img, ru, m1);
  k_transpose<<<(410 * 1568 + 255) / 256, 256, 0, stream>>>(wf1, wt);
  k_conv1<<<B * 16, 256, 0, stream>>>(m1, w1, m2);
  k_conv2<<<B * 32, 256, 0, stream>>>(m2, w2, m4);
  k_dense1<<<dim3(7, 200), 256, 0, stream>>>(m4, wt, d5);
  k_psp5<<<(B * 410 + 255) / 256, 256, 0, stream>>>(d5, s5);
  k_dense2<<<(B * T * 10 + 255) / 256, 256, 0, stream>>>(s5, wf2, d6);
  k_psp6<<<2, 256, 0, stream>>>(d6, out);
}

// Round 7
// 762.379 us; speedup vs baseline: 1.3404x; 1.3404x over previous
//
#include <hip/hip_runtime.h>

// ---------------------------------------------------------------------------
// SLAYER-style spiking CNN forward pass, MI355X.  Round 7.
//
// psp (SRM alpha kernel) as double-exponential IIR cascade (exact):
//   g1[t] = x[t] + a*g1[t-1]; g2[t] = g1[t] + a*g2[t-1]; u = (e/tau)*(g2-g1)
//
// R7: dense1 back to FIXED-TRIP loops (R5/R6's data-dependent while loop
// defeated unrolling/pipelining -> one unhidden L2 round-trip per iteration,
// VALUBusy 15%).  Dense walk over all 49 bits per ob-block: predictable
// load addresses (compiler pipelines), multiplier = scalar-selected 0/1
// (fma(w,0,a) is IEEE-exact; ascending-i order == R2's passing dense loop).
// All accumulation in f64 for exact spike-pattern match.
// ---------------------------------------------------------------------------

namespace {
constexpr int B = 32, T = 100;
constexpr double A1 = 0.90483741803595957;  // exp(-1/10)
constexpr double CE = 0.27182818284590452;  // e/10

// workspace byte offsets
constexpr size_t OFF_M1 = 0;                                  // u32 [B*T][28]
constexpr size_t OFF_M2 = OFF_M1 + (size_t)B * T * 28 * 4;    // u32 [B*T][16][14]
constexpr size_t OFF_M4 = OFF_M2 + (size_t)B * T * 224 * 4;   // u64 [B*T][32]
constexpr size_t OFF_D5 = OFF_M4 + (size_t)B * T * 32 * 8;    // f64 [B*T][410]
constexpr size_t OFF_S5 = OFF_D5 + (size_t)B * T * 410 * 8;   // u8  [B*T][410]
constexpr size_t OFF_D6 = OFF_S5 + (size_t)B * T * 410;       // f64 [B*T][10]
constexpr size_t OFF_WT = OFF_D6 + (size_t)B * T * 10 * 8;    // f32 [1568][410]
}  // namespace

// Zero-extending wave-uniform u64 broadcast (readfirstlane returns int —
// implicit conversion would SIGN-extend; that was the R3/R4 bug).
__device__ inline unsigned long long uniform_u64(unsigned long long v) {
  unsigned int lo = (unsigned int)__builtin_amdgcn_readfirstlane((int)(unsigned int)v);
  unsigned int hi = (unsigned int)__builtin_amdgcn_readfirstlane((int)(unsigned int)(v >> 32));
  return ((unsigned long long)hi << 32) | (unsigned long long)lo;
}

// Stage 0: rate encode + bit-pack rows.
__global__ void k_encode_pack(const float* __restrict__ img, const float* __restrict__ ru,
                              unsigned int* __restrict__ m1) {
  int i = blockIdx.x * 256 + threadIdx.x;
  if (i >= B * 28 * T) return;
  int t = i % T;
  int y = (i / T) % 28;
  int b = i / (T * 28);
  unsigned int m = 0;
  const float* rb = ru + ((size_t)b * 784 + y * 28) * T + t;
  const float* ib = img + b * 784 + y * 28;
  for (int x = 0; x < 28; x++) {
    m |= (rb[(size_t)x * T] < ib[x]) ? (1u << x) : 0u;
  }
  m1[((size_t)b * T + t) * 28 + y] = m;
}

// Stage 1 fused: conv1 (1->16,5x5,pad2) + psp + spike + pool2 + psp + spike.
__global__ __launch_bounds__(256) void k_conv1(const unsigned int* __restrict__ m1,
                                               const float* __restrict__ w1,
                                               unsigned int* __restrict__ m2) {
  __shared__ double lut[160];        // [dy][32]
  __shared__ unsigned int mrow[32];  // rows iy=-2..29 at idx iy+2; guards 0
  __shared__ unsigned char spk[784];
  __shared__ unsigned char spkP[196];
  int o = blockIdx.x % 16, b = blockIdx.x / 16;
  int tid = threadIdx.x;
  if (tid < 160) {
    int dy = tid / 32, f = tid % 32;
    double v = 0.0;
    const float* wb = w1 + o * 25 + dy * 5;
#pragma unroll
    for (int dx = 0; dx < 5; dx++)
      if ((f >> dx) & 1) v += (double)wb[dx];
    lut[tid] = v;
  }
  if (tid < 32) mrow[tid] = 0;  // guard rows stay 0
  int y = tid / 7, xg = tid % 7;     // conv coords: 28 rows x 7 groups of 4 px
  int py = tid / 14, px = tid % 14;  // pooled coords
  bool act = tid < 196;
  double g1[4] = {0, 0, 0, 0}, g2[4] = {0, 0, 0, 0};
  double p1 = 0.0, p2 = 0.0;
  const unsigned int* m1b = m1 + (size_t)b * T * 28;
  unsigned int r = (tid < 28) ? m1b[tid] : 0u;  // prefetch t=0
  for (int t = 0; t < T; t++) {
    __syncthreads();
    if (tid < 28) mrow[tid + 2] = r << 2;  // pre-shifted
    __syncthreads();
    if (tid < 28 && t + 1 < T) r = m1b[(t + 1) * 28 + tid];  // prefetch t+1
    if (act) {
      double s0 = 0, s1 = 0, s2 = 0, s3 = 0;
      int xb = xg * 4;
#pragma unroll
      for (int dy = 0; dy < 5; dy++) {
        unsigned int m = mrow[y + dy];
        const double* ld = lut + dy * 32;
        s0 += ld[(m >> (xb + 0)) & 31];
        s1 += ld[(m >> (xb + 1)) & 31];
        s2 += ld[(m >> (xb + 2)) & 31];
        s3 += ld[(m >> (xb + 3)) & 31];
      }
      g1[0] = s0 + A1 * g1[0]; g2[0] = g1[0] + A1 * g2[0];
      g1[1] = s1 + A1 * g1[1]; g2[1] = g1[1] + A1 * g2[1];
      g1[2] = s2 + A1 * g1[2]; g2[2] = g1[2] + A1 * g2[2];
      g1[3] = s3 + A1 * g1[3]; g2[3] = g1[3] + A1 * g2[3];
      unsigned char* sp = spk + y * 28 + xb;
      sp[0] = (CE * (g2[0] - g1[0]) >= 1.0) ? 1 : 0;
      sp[1] = (CE * (g2[1] - g1[1]) >= 1.0) ? 1 : 0;
      sp[2] = (CE * (g2[2] - g1[2]) >= 1.0) ? 1 : 0;
      sp[3] = (CE * (g2[3] - g1[3]) >= 1.0) ? 1 : 0;
    }
    __syncthreads();
    if (act) {
      const unsigned char* r0 = spk + (2 * py) * 28 + 2 * px;
      int sum = (int)r0[0] + (int)r0[1] + (int)r0[28] + (int)r0[29];
      double s = 1.1 * (double)sum;
      p1 = s + A1 * p1;
      p2 = p1 + A1 * p2;
      spkP[tid] = (CE * (p2 - p1) >= 1.0) ? 1 : 0;
    }
    __syncthreads();
    if (tid < 14) {
      unsigned int m = 0;
      const unsigned char* rp = spkP + tid * 14;
#pragma unroll
      for (int xx = 0; xx < 14; xx++) m |= ((unsigned int)rp[xx]) << xx;
      m2[((size_t)(b * T + t) * 16 + o) * 14 + tid] = m;
    }
  }
}

// Stage 3 fused: conv2 (16->32,5x5,pad2) + psp + spike + pool2 + psp + spike.
// Emits pooled spikes as u64 ballot masks m4[bt][o] (bit p = pooled pos p).
__global__ __launch_bounds__(256) void k_conv2(const unsigned int* __restrict__ m2,
                                               const float* __restrict__ w2,
                                               unsigned long long* __restrict__ m4) {
  __shared__ double lut[2560];         // [ci][dy][32]  (20480 B)
  __shared__ unsigned int mrow2[288];  // [row 0..17][ci 0..15]; guard rows 0
  __shared__ unsigned char spk[196];
  int o = blockIdx.x % 32, b = blockIdx.x / 32;
  int tid = threadIdx.x;
  for (int e = tid; e < 2560; e += 256) {
    int ci = e / 160, rr = e % 160, dy = rr / 32, f = rr % 32;
    double v = 0.0;
    const float* wb = w2 + o * 400 + ci * 25 + dy * 5;
#pragma unroll
    for (int dx = 0; dx < 5; dx++)
      if ((f >> dx) & 1) v += (double)wb[dx];
    lut[e] = v;  // e == (ci*5+dy)*32 + f
  }
  for (int k = tid; k < 288; k += 256) mrow2[k] = 0;
  int y = tid / 14, x = tid % 14;
  int py = tid / 7, px = tid % 7;
  bool act = tid < 196;
  double g1 = 0.0, g2 = 0.0, p1 = 0.0, p2 = 0.0;
  const unsigned int* m2b = m2 + (size_t)b * T * 224;
  int ci = tid / 14, rr = tid % 14;
  unsigned int r = (tid < 224) ? m2b[tid] : 0u;  // prefetch t=0
  for (int t = 0; t < T; t++) {
    __syncthreads();
    if (tid < 224) mrow2[(rr + 2) * 16 + ci] = r << 2;  // pre-shifted
    __syncthreads();
    if (tid < 224 && t + 1 < T) r = m2b[(size_t)(t + 1) * 224 + tid];  // prefetch
    if (act) {
      double s = 0.0;
#pragma unroll
      for (int dy = 0; dy < 5; dy++) {
        const uint4* q = (const uint4*)(mrow2 + (y + dy) * 16);
        uint4 qa = q[0], qb = q[1], qc = q[2], qd = q[3];
        const double* ld = lut + dy * 32;
        s += ld[0 * 160 + ((qa.x >> x) & 31)];
        s += ld[1 * 160 + ((qa.y >> x) & 31)];
        s += ld[2 * 160 + ((qa.z >> x) & 31)];
        s += ld[3 * 160 + ((qa.w >> x) & 31)];
        s += ld[4 * 160 + ((qb.x >> x) & 31)];
        s += ld[5 * 160 + ((qb.y >> x) & 31)];
        s += ld[6 * 160 + ((qb.z >> x) & 31)];
        s += ld[7 * 160 + ((qb.w >> x) & 31)];
        s += ld[8 * 160 + ((qc.x >> x) & 31)];
        s += ld[9 * 160 + ((qc.y >> x) & 31)];
        s += ld[10 * 160 + ((qc.z >> x) & 31)];
        s += ld[11 * 160 + ((qc.w >> x) & 31)];
        s += ld[12 * 160 + ((qd.x >> x) & 31)];
        s += ld[13 * 160 + ((qd.y >> x) & 31)];
        s += ld[14 * 160 + ((qd.z >> x) & 31)];
        s += ld[15 * 160 + ((qd.w >> x) & 31)];
      }
      g1 = s + A1 * g1;
      g2 = g1 + A1 * g2;
      spk[tid] = (CE * (g2 - g1) >= 1.0) ? 1 : 0;
    }
    __syncthreads();
    bool sp = false;
    if (tid < 49) {
      const unsigned char* r0 = spk + (2 * py) * 14 + 2 * px;
      int sum = (int)r0[0] + (int)r0[1] + (int)r0[14] + (int)r0[15];
      double s = 1.1 * (double)sum;
      p1 = s + A1 * p1;
      p2 = p1 + A1 * p2;
      sp = (CE * (p2 - p1) >= 1.0);
    }
    unsigned long long bal = __ballot(sp);  // bits 0..48 live in wave 0
    if (tid == 0) m4[(size_t)(b * T + t) * 32 + o] = bal;
  }
}

// Transpose wf1 [410][1568] -> wt [1568][410] for coalesced dense1 reads.
__global__ void k_transpose(const float* __restrict__ wf1, float* __restrict__ wt) {
  int i = blockIdx.x * 256 + threadIdx.x;
  if (i >= 410 * 1568) return;
  int col = i % 410, row = i / 410;
  wt[i] = wf1[col * 1568 + row];
}

// Stage 5a: dense1 matmul.  Wave = 64 o-lanes, 4 (b,t) columns/wave.
// Fixed-trip dense walk: one coalesced weight load per (ob,k) feeds 4
// f64 FMAs with wave-uniform scalar-selected 0/1 multipliers (fma(w,0,a)
// is IEEE-exact; ascending-i term order == R2's passing dense loop).
// Predictable addresses -> compiler unrolls & pipelines the loads.
__global__ __launch_bounds__(256) void k_dense1(const unsigned long long* __restrict__ m4,
                                                const float* __restrict__ wt,
                                                double* __restrict__ d5) {
  int tid = threadIdx.x;
  int lane = tid & 63;
  int wv = tid >> 6;
  int o = blockIdx.x * 64 + lane;  // gridDim.x = 7
  bool store = o < 410;
  int osafe = store ? o : 409;
  int col0 = (blockIdx.y * 4 + wv) * 4;  // gridDim.y = 200
  const float* wb = wt + osafe;
  const unsigned long long* mm = m4 + (size_t)col0 * 32;
  double a0 = 0, a1 = 0, a2 = 0, a3 = 0;
  for (int ob = 0; ob < 32; ob++) {
    unsigned long long q0 = uniform_u64(mm[ob]);
    unsigned long long q1 = uniform_u64(mm[32 + ob]);
    unsigned long long q2 = uniform_u64(mm[64 + ob]);
    unsigned long long q3 = uniform_u64(mm[96 + ob]);
    if (!(q0 | q1 | q2 | q3)) continue;  // adds nothing — exact skip
    const float* wob = wb + ob * 49 * 410;
#pragma unroll 7
    for (int k = 0; k < 49; k++) {
      double w = (double)wob[k * 410];
      double b0 = ((q0 >> k) & 1) ? 1.0 : 0.0;
      double b1 = ((q1 >> k) & 1) ? 1.0 : 0.0;
      double b2 = ((q2 >> k) & 1) ? 1.0 : 0.0;
      double b3 = ((q3 >> k) & 1) ? 1.0 : 0.0;
      a0 = __builtin_fma(w, b0, a0);
      a1 = __builtin_fma(w, b1, a1);
      a2 = __builtin_fma(w, b2, a2);
      a3 = __builtin_fma(w, b3, a3);
    }
  }
  if (store) {
    d5[(size_t)(col0 + 0) * 410 + o] = a0;
    d5[(size_t)(col0 + 1) * 410 + o] = a1;
    d5[(size_t)(col0 + 2) * 410 + o] = a2;
    d5[(size_t)(col0 + 3) * 410 + o] = a3;
  }
}

// Stage 5b: psp + spike over dense1 output.  One thread per (b,o).
__global__ void k_psp5(const double* __restrict__ d5, unsigned char* __restrict__ s5) {
  int tid = blockIdx.x * 256 + threadIdx.x;
  if (tid >= B * 410) return;
  int o = tid % 410, b = tid / 410;
  double g1 = 0.0, g2 = 0.0;
  for (int t = 0; t < T; t++) {
    double s = d5[(size_t)(b * T + t) * 410 + o];
    g1 = s + A1 * g1;
    g2 = g1 + A1 * g2;
    s5[(size_t)(b * T + t) * 410 + o] = (CE * (g2 - g1) >= 1.0) ? 1 : 0;
  }
}

// Stage 6a: dense2 matmul.  One thread per (bt,o).
__global__ void k_dense2(const unsigned char* __restrict__ s5, const float* __restrict__ wf2,
                         double* __restrict__ d6) {
  int tid = blockIdx.x * 256 + threadIdx.x;
  if (tid >= B * T * 10) return;
  int o = tid % 10, bt = tid / 10;
  const unsigned char* sr = s5 + (size_t)bt * 410;
  const float* wr = wf2 + o * 410;
  double s = 0.0;
  for (int i = 0; i < 410; i++) s += (double)wr[i] * (double)sr[i];
  d6[tid] = s;
}

// Stage 6b: final psp + spike -> d_out [b][o][t] f32.
__global__ void k_psp6(const double* __restrict__ d6, float* __restrict__ out) {
  int tid = blockIdx.x * 256 + threadIdx.x;
  if (tid >= B * 10) return;
  int o = tid % 10, b = tid / 10;
  double g1 = 0.0, g2 = 0.0;
  for (int t = 0; t < T; t++) {
    double s = d6[(size_t)(b * T + t) * 10 + o];
    g1 = s + A1 * g1;
    g2 = g1 + A1 * g2;
    out[(size_t)b * 1000 + o * 100 + t] = (CE * (g2 - g1) >= 1.0) ? 1.0f : 0.0f;
  }
}

extern "C" void kernel_launch(void* const* d_in, const int* in_sizes, int n_in,
                              void* d_out, int out_size, void* d_ws, size_t ws_size,
                              hipStream_t stream) {
  const float* img = (const float*)d_in[0];
  const float* ru = (const float*)d_in[1];
  const float* w1 = (const float*)d_in[2];
  const float* w2 = (const float*)d_in[3];
  const float* wf1 = (const float*)d_in[4];
  const float* wf2 = (const float*)d_in[5];

  unsigned char* ws = (unsigned char*)d_ws;
  unsigned int* m1 = (unsigned int*)(ws + OFF_M1);
  unsigned int* m2 = (unsigned int*)(ws + OFF_M2);
  unsigned long long* m4 = (unsigned long long*)(ws + OFF_M4);
  double* d5 = (double*)(ws + OFF_D5);
  unsigned char* s5 = ws + OFF_S5;
  double* d6 = (double*)(ws + OFF_D6);
  float* wt = (float*)(ws + OFF_WT);
  float* out = (float*)d_out;

  k_encode_pack<<<(B * 28 * T + 255) / 256, 256, 0, stream>>>(img, ru, m1);
  k_transpose<<<(410 * 1568 + 255) / 256, 256, 0, stream>>>(wf1, wt);
  k_conv1<<<B * 16, 256, 0, stream>>>(m1, w1, m2);
  k_conv2<<<B * 32, 256, 0, stream>>>(m2, w2, m4);
  k_dense1<<<dim3(7, 200), 256, 0, stream>>>(m4, wt, d5);
  k_psp5<<<(B * 410 + 255) / 256, 256, 0, stream>>>(d5, s5);
  k_dense2<<<(B * T * 10 + 255) / 256, 256, 0, stream>>>(s5, wf2, d6);
  k_psp6<<<2, 256, 0, stream>>>(d6, out);
}